// Round 2
// baseline (533.808 us; speedup 1.0000x reference)
//
#include <hip/hip_runtime.h>

typedef unsigned short u16;
typedef unsigned int u32;
typedef __bf16 bf16x8 __attribute__((ext_vector_type(8)));
typedef float f32x4 __attribute__((ext_vector_type(4)));

#define EPS 1e-5f
#define INV_NORM 0.088388347648318447f  // 1/sqrt(128)

// d_out element offsets (fp32 elements)
#define OUT_W   0
#define OUT_LOG 2097152
#define OUT_LP  4194304
#define OUT_S   6291456

// d_ws layout (u16 element offsets)
#define WS_BT   0            // Bt: 16384 x 512 bf16
#define WS_LAT  8388608      // latbf: 510 x 128 bf16 (pad to 65536)
#define WS_A    8454144      // Abf: 4096 x 512 bf16

__device__ __forceinline__ u16 f2b(float f) {
  u32 i = __float_as_uint(f);
  return (u16)((i + 0x7FFFu + ((i >> 16) & 1u)) >> 16);  // RNE
}
__device__ __forceinline__ float wsum(float v) {
#pragma unroll
  for (int off = 32; off > 0; off >>= 1) v += __shfl_down(v, off, 64);
  return v;
}
__device__ __forceinline__ float wmax(float v) {
#pragma unroll
  for (int off = 32; off > 0; off >>= 1) v = fmaxf(v, __shfl_down(v, off, 64));
  return v;
}
// dot of 8 packed bf16 (uint4) against 8 LDS floats
__device__ __forceinline__ float dot8(uint4 u, const float* xp) {
  float s;
  s  = xp[0] * __uint_as_float(u.x << 16);
  s += xp[1] * __uint_as_float(u.x & 0xFFFF0000u);
  s += xp[2] * __uint_as_float(u.y << 16);
  s += xp[3] * __uint_as_float(u.y & 0xFFFF0000u);
  s += xp[4] * __uint_as_float(u.z << 16);
  s += xp[5] * __uint_as_float(u.z & 0xFFFF0000u);
  s += xp[6] * __uint_as_float(u.w << 16);
  s += xp[7] * __uint_as_float(u.w & 0xFFFF0000u);
  return s;
}
// dot of float4 against 4 LDS floats
__device__ __forceinline__ float dot4(float4 u, const float* xp) {
  return xp[0] * u.x + xp[1] * u.y + xp[2] * u.z + xp[3] * u.w;
}

// ---------------- K1: lat = LN(latents @ linear_w^T + linear_b) -> bf16 ----
__global__ __launch_bounds__(128) void k_lat(const float* __restrict__ latents,
                                             const float* __restrict__ lw,
                                             const float* __restrict__ lb,
                                             u16* __restrict__ latbf) {
  int k = blockIdx.x, t = threadIdx.x;
  int wid = t >> 6, lane = t & 63;
  __shared__ float ls[256];
  __shared__ float red[4];
  ls[t] = latents[k * 256 + t];
  ls[t + 128] = latents[k * 256 + 128 + t];
  __syncthreads();
  float v = lb[t];
  const float4* wv = (const float4*)(lw + t * 256);
#pragma unroll
  for (int c = 0; c < 64; c++) v += dot4(wv[c], &ls[c * 4]);
  float s = wsum(v), s2 = wsum(v * v);
  if (lane == 0) { red[wid * 2] = s; red[wid * 2 + 1] = s2; }
  __syncthreads();
  float mean = (red[0] + red[2]) * 0.0078125f;
  float var = (red[1] + red[3]) * 0.0078125f - mean * mean;
  latbf[k * 128 + t] = f2b((v - mean) * rsqrtf(var + EPS));
}

// ---------------- K2: Bt[n][k] = bf16(sprite[k][n]), n=ch*4096+hw ----------
__global__ __launch_bounds__(256) void k_tr(const float* __restrict__ proto,
                                            const float* __restrict__ masks,
                                            u16* __restrict__ Bt) {
  __shared__ u16 tile[64 * 72];  // [k-local][n-local], pad 72
  int t = threadIdx.x;
  int n0 = blockIdx.x * 64;
  int k0 = blockIdx.y * 64;
  int ch = n0 >> 12, hw0 = n0 & 4095;
  int r = t >> 2, c = (t & 3) * 16;
  int kg = k0 + r;
  u16 vals[16];
#pragma unroll
  for (int e = 0; e < 16; e++) vals[e] = 0;
  if (kg < 510) {
    const float* src = (ch < 3) ? (proto + ((size_t)kg * 3 + ch) * 4096 + hw0 + c)
                                : (masks + (size_t)kg * 4096 + hw0 + c);
    const float4* s4 = (const float4*)src;
#pragma unroll
    for (int q = 0; q < 4; q++) {
      float4 u = s4[q];
      vals[q * 4 + 0] = f2b(u.x);
      vals[q * 4 + 1] = f2b(u.y);
      vals[q * 4 + 2] = f2b(u.z);
      vals[q * 4 + 3] = f2b(u.w);
    }
  }
#pragma unroll
  for (int e = 0; e < 16; e++) tile[r * 72 + c + e] = vals[e];
  __syncthreads();
  int nr = t >> 2, kc = (t & 3) * 16;
  u32 u[8];
#pragma unroll
  for (int e = 0; e < 8; e++) {
    u32 lo = tile[(kc + 2 * e) * 72 + nr];
    u32 hi = tile[(kc + 2 * e + 1) * 72 + nr];
    u[e] = lo | (hi << 16);
  }
  u16* dst = Bt + (size_t)(n0 + nr) * 512 + k0 + kc;
  uint4 v0 = {u[0], u[1], u[2], u[3]};
  uint4 v1 = {u[4], u[5], u[6], u[7]};
  *(uint4*)dst = v0;
  *(uint4*)(dst + 8) = v1;
}

// ---------------- K3: per-row anchors+LN+logits+blank+softmax --------------
__global__ __launch_bounds__(128) void k_rows(const float* __restrict__ x,
                                              const float* __restrict__ aw,
                                              const float* __restrict__ ab,
                                              const float* __restrict__ blank,
                                              const u16* __restrict__ latbf,
                                              float* __restrict__ out,
                                              u16* __restrict__ Abf) {
  int n = blockIdx.x;
  int b = n >> 7, p = n & 127;
  int t = threadIdx.x, wid = t >> 6, lane = t & 63;
  __shared__ float xs[128];
  __shared__ float ash[128];
  __shared__ float red[8];
  xs[t] = x[(size_t)b * 16384 + (size_t)t * 128 + p];
  __syncthreads();
  float av = ab[t];
  const float4* awv = (const float4*)(aw + t * 128);
#pragma unroll
  for (int c = 0; c < 32; c++) av += dot4(awv[c], &xs[c * 4]);
  float bv = xs[t] * blank[(p & 1) * 128 + t];
  float s = wsum(av), s2 = wsum(av * av), sb = wsum(bv);
  if (lane == 0) { red[wid * 3] = s; red[wid * 3 + 1] = s2; red[wid * 3 + 2] = sb; }
  __syncthreads();
  float mean = (red[0] + red[3]) * 0.0078125f;
  float var = (red[1] + red[4]) * 0.0078125f - mean * mean;
  float dots = red[2] + red[5];
  float an = (av - mean) * rsqrtf(var + EPS);
  ash[t] = an;
  float bl = dots * INV_NORM;
  __syncthreads();  // ash visible to all
  float l[4];
  float lmax = -1e30f;
#pragma unroll
  for (int i = 0; i < 4; i++) {
    int k = i * 128 + t;
    float v;
    if (k < 510) {
      const uint4* lv = (const uint4*)(latbf + k * 128);
      float acc = 0.f;
#pragma unroll
      for (int c = 0; c < 16; c++) acc += dot8(lv[c], &ash[c * 8]);
      v = acc * INV_NORM;
    } else {
      v = bl;  // blank columns 510,511
    }
    l[i] = v;
    lmax = fmaxf(lmax, v);
  }
  float m = wmax(lmax);
  __syncthreads();  // red reuse
  if (lane == 0) red[wid] = m;
  __syncthreads();
  float M = fmaxf(red[0], red[1]);
  float se = 0.f;
#pragma unroll
  for (int i = 0; i < 4; i++) se += expf(l[i] - M);
  float ssum = wsum(se);
  __syncthreads();  // red reuse
  if (lane == 0) red[wid] = ssum;
  __syncthreads();
  float S = red[0] + red[1];
  float logZ = M + logf(S);
  size_t nb = (size_t)n * 512;
  size_t lpb = (size_t)OUT_LP + ((size_t)p * 32 + b) * 512;
#pragma unroll
  for (int i = 0; i < 4; i++) {
    int k = i * 128 + t;
    float lp = l[i] - logZ;
    float w = expf(lp);
    out[OUT_W + nb + k] = w;
    out[OUT_LOG + nb + k] = l[i];
    out[lpb + k] = lp;
    Abf[nb + k] = f2b(w);
  }
}

// ---------------- K4: S_out = (weights @ sprite) permuted, bf16 MFMA -------
__global__ __launch_bounds__(256) void k_gemm(const u16* __restrict__ A,
                                              const u16* __restrict__ Bt,
                                              float* __restrict__ out) {
  __shared__ u16 As[128 * 32];
  __shared__ u16 Bs[128 * 32];
  int tid = threadIdx.x;
  int wid = tid >> 6, lane = tid & 63;
  int nBase = blockIdx.x * 128;
  int mBase = blockIdx.y * 128;
  int wm = wid >> 1, wn = wid & 1;
  int quad = lane >> 4, r16 = lane & 15;
  f32x4 acc[4][4];
#pragma unroll
  for (int i = 0; i < 4; i++)
#pragma unroll
    for (int j = 0; j < 4; j++) acc[i][j] = (f32x4){0.f, 0.f, 0.f, 0.f};

  int srow = wid * 32 + (lane >> 2);   // row this lane stages (c adds 16)
  int koff = (lane & 3) * 8;           // k offset within BK=32
  char* ldsA = (char*)As + wid * 2048;
  char* ldsB = (char*)Bs + wid * 2048;

  for (int kt = 0; kt < 16; kt++) {
    int k0 = kt * 32;
#pragma unroll
    for (int c = 0; c < 2; c++) {
      const u16* ga = A + (size_t)(mBase + srow + c * 16) * 512 + k0 + koff;
      const u16* gb = Bt + (size_t)(nBase + srow + c * 16) * 512 + k0 + koff;
      __builtin_amdgcn_global_load_lds(
          (__attribute__((address_space(1))) void*)ga,
          (__attribute__((address_space(3))) void*)(ldsA + c * 1024), 16, 0, 0);
      __builtin_amdgcn_global_load_lds(
          (__attribute__((address_space(1))) void*)gb,
          (__attribute__((address_space(3))) void*)(ldsB + c * 1024), 16, 0, 0);
    }
    __syncthreads();
    bf16x8 af[4], bfr[4];
#pragma unroll
    for (int i = 0; i < 4; i++)
      af[i] = *(const bf16x8*)&As[(wm * 64 + i * 16 + r16) * 32 + quad * 8];
#pragma unroll
    for (int j = 0; j < 4; j++)
      bfr[j] = *(const bf16x8*)&Bs[(wn * 64 + j * 16 + r16) * 32 + quad * 8];
#pragma unroll
    for (int i = 0; i < 4; i++)
#pragma unroll
      for (int j = 0; j < 4; j++)
        acc[i][j] = __builtin_amdgcn_mfma_f32_16x16x32_bf16(af[i], bfr[j],
                                                            acc[i][j], 0, 0, 0);
    __syncthreads();
  }
#pragma unroll
  for (int i = 0; i < 4; i++) {
#pragma unroll
    for (int r = 0; r < 4; r++) {
      int mg = mBase + wm * 64 + i * 16 + quad * 4 + r;
      size_t orow = (size_t)((mg & 127) * 32 + (mg >> 7));  // p*32 + b
      float* orp = out + OUT_S + orow * 16384 + nBase + wn * 64 + r16;
#pragma unroll
      for (int j = 0; j < 4; j++) orp[j * 16] = acc[i][j][r];
    }
  }
}

extern "C" void kernel_launch(void* const* d_in, const int* in_sizes, int n_in,
                              void* d_out, int out_size, void* d_ws, size_t ws_size,
                              hipStream_t stream) {
  const float* x = (const float*)d_in[0];
  const float* latents = (const float*)d_in[1];
  const float* blank = (const float*)d_in[2];
  const float* lw = (const float*)d_in[3];
  const float* lb = (const float*)d_in[4];
  const float* aw = (const float*)d_in[5];
  const float* ab = (const float*)d_in[6];
  const float* proto = (const float*)d_in[7];
  const float* masks = (const float*)d_in[8];
  float* out = (float*)d_out;
  u16* ws16 = (u16*)d_ws;
  u16* Bt = ws16 + WS_BT;
  u16* latbf = ws16 + WS_LAT;
  u16* Abf = ws16 + WS_A;

  k_lat<<<510, 128, 0, stream>>>(latents, lw, lb, latbf);
  k_tr<<<dim3(256, 8), 256, 0, stream>>>(proto, masks, Bt);
  k_rows<<<4096, 128, 0, stream>>>(x, aw, ab, blank, latbf, out, Abf);
  k_gemm<<<dim3(128, 32), 256, 0, stream>>>(Abf, Bt, out);
}

// Round 3
// 514.888 us; speedup vs baseline: 1.0367x; 1.0367x over previous
//
#include <hip/hip_runtime.h>

typedef unsigned short u16;
typedef unsigned int u32;
typedef __bf16 bf16x8 __attribute__((ext_vector_type(8)));
typedef float f32x4 __attribute__((ext_vector_type(4)));

#define EPS 1e-5f
#define INV_NORM 0.088388347648318447f  // 1/sqrt(128)

// d_out element offsets (fp32 elements)
#define OUT_W   0
#define OUT_LOG 2097152
#define OUT_LP  4194304
#define OUT_S   6291456

// d_ws layout (u16 element offsets)
#define WS_BT   0            // Bt: 16384 x 512 bf16
#define WS_LAT  8388608      // latbf: 512 x 128 bf16 (rows 510/511 garbage, unused)
#define WS_A    8454144      // Abf: 4096 x 512 bf16

__device__ __forceinline__ u16 f2b(float f) {
  u32 i = __float_as_uint(f);
  return (u16)((i + 0x7FFFu + ((i >> 16) & 1u)) >> 16);  // RNE
}
__device__ __forceinline__ float wsum(float v) {
#pragma unroll
  for (int off = 32; off > 0; off >>= 1) v += __shfl_down(v, off, 64);
  return v;
}
__device__ __forceinline__ float wmax(float v) {
#pragma unroll
  for (int off = 32; off > 0; off >>= 1) v = fmaxf(v, __shfl_down(v, off, 64));
  return v;
}
// dot of 8 packed bf16 (uint4) against 8 LDS floats
__device__ __forceinline__ float dot8(uint4 u, const float* xp) {
  float s;
  s  = xp[0] * __uint_as_float(u.x << 16);
  s += xp[1] * __uint_as_float(u.x & 0xFFFF0000u);
  s += xp[2] * __uint_as_float(u.y << 16);
  s += xp[3] * __uint_as_float(u.y & 0xFFFF0000u);
  s += xp[4] * __uint_as_float(u.z << 16);
  s += xp[5] * __uint_as_float(u.z & 0xFFFF0000u);
  s += xp[6] * __uint_as_float(u.w << 16);
  s += xp[7] * __uint_as_float(u.w & 0xFFFF0000u);
  return s;
}
// dot of float4 against 4 LDS floats
__device__ __forceinline__ float dot4(float4 u, const float* xp) {
  return xp[0] * u.x + xp[1] * u.y + xp[2] * u.z + xp[3] * u.w;
}

// ---------------- K1: lat = LN(latents @ linear_w^T + linear_b) -> bf16 ----
__global__ __launch_bounds__(128) void k_lat(const float* __restrict__ latents,
                                             const float* __restrict__ lw,
                                             const float* __restrict__ lb,
                                             u16* __restrict__ latbf) {
  int k = blockIdx.x, t = threadIdx.x;
  int wid = t >> 6, lane = t & 63;
  __shared__ float ls[256];
  __shared__ float red[4];
  ls[t] = latents[k * 256 + t];
  ls[t + 128] = latents[k * 256 + 128 + t];
  __syncthreads();
  float v = lb[t];
  const float4* wv = (const float4*)(lw + t * 256);
#pragma unroll
  for (int c = 0; c < 64; c++) v += dot4(wv[c], &ls[c * 4]);
  float s = wsum(v), s2 = wsum(v * v);
  if (lane == 0) { red[wid * 2] = s; red[wid * 2 + 1] = s2; }
  __syncthreads();
  float mean = (red[0] + red[2]) * 0.0078125f;
  float var = (red[1] + red[3]) * 0.0078125f - mean * mean;
  latbf[k * 128 + t] = f2b((v - mean) * rsqrtf(var + EPS));
}

// ---------------- K2: Bt[n][k] = bf16(sprite[k][n]), n=ch*4096+hw ----------
__global__ __launch_bounds__(256) void k_tr(const float* __restrict__ proto,
                                            const float* __restrict__ masks,
                                            u16* __restrict__ Bt) {
  __shared__ u16 tile[64 * 72];  // [k-local][n-local], pad 72
  int t = threadIdx.x;
  int n0 = blockIdx.x * 64;
  int k0 = blockIdx.y * 64;
  int ch = n0 >> 12, hw0 = n0 & 4095;
  int r = t >> 2, c = (t & 3) * 16;
  int kg = k0 + r;
  u16 vals[16];
#pragma unroll
  for (int e = 0; e < 16; e++) vals[e] = 0;
  if (kg < 510) {
    const float* src = (ch < 3) ? (proto + ((size_t)kg * 3 + ch) * 4096 + hw0 + c)
                                : (masks + (size_t)kg * 4096 + hw0 + c);
    const float4* s4 = (const float4*)src;
#pragma unroll
    for (int q = 0; q < 4; q++) {
      float4 u = s4[q];
      vals[q * 4 + 0] = f2b(u.x);
      vals[q * 4 + 1] = f2b(u.y);
      vals[q * 4 + 2] = f2b(u.z);
      vals[q * 4 + 3] = f2b(u.w);
    }
  }
#pragma unroll
  for (int e = 0; e < 16; e++) tile[r * 72 + c + e] = vals[e];
  __syncthreads();
  int nr = t >> 2, kc = (t & 3) * 16;
  u32 u[8];
#pragma unroll
  for (int e = 0; e < 8; e++) {
    u32 lo = tile[(kc + 2 * e) * 72 + nr];
    u32 hi = tile[(kc + 2 * e + 1) * 72 + nr];
    u[e] = lo | (hi << 16);
  }
  u16* dst = Bt + (size_t)(n0 + nr) * 512 + k0 + kc;
  uint4 v0 = {u[0], u[1], u[2], u[3]};
  uint4 v1 = {u[4], u[5], u[6], u[7]};
  *(uint4*)dst = v0;
  *(uint4*)(dst + 8) = v1;
}

// ---------------- K3: per-row anchors+LN+logits+blank+softmax --------------
__global__ __launch_bounds__(128) void k_rows(const float* __restrict__ x,
                                              const float* __restrict__ aw,
                                              const float* __restrict__ ab,
                                              const float* __restrict__ blank,
                                              const u16* __restrict__ latbf,
                                              float* __restrict__ out,
                                              u16* __restrict__ Abf) {
  int n = blockIdx.x;
  int b = n >> 7, p = n & 127;
  int t = threadIdx.x, wid = t >> 6, lane = t & 63;
  __shared__ float xs[128];
  __shared__ float ash[128];
  __shared__ float red[8];
  xs[t] = x[(size_t)b * 16384 + (size_t)t * 128 + p];
  __syncthreads();
  float av = ab[t];
  const float4* awv = (const float4*)(aw + t * 128);
#pragma unroll
  for (int c = 0; c < 32; c++) av += dot4(awv[c], &xs[c * 4]);
  float bv = xs[t] * blank[(p & 1) * 128 + t];
  float s = wsum(av), s2 = wsum(av * av), sb = wsum(bv);
  if (lane == 0) { red[wid * 3] = s; red[wid * 3 + 1] = s2; red[wid * 3 + 2] = sb; }
  __syncthreads();
  float mean = (red[0] + red[3]) * 0.0078125f;
  float var = (red[1] + red[4]) * 0.0078125f - mean * mean;
  float dots = red[2] + red[5];
  float an = (av - mean) * rsqrtf(var + EPS);
  ash[t] = an;
  float bl = dots * INV_NORM;
  __syncthreads();  // ash visible to all
  // thread t owns k = 4t .. 4t+3 (consecutive -> float4 stores)
  const uint4* lv = (const uint4*)(latbf + (size_t)(4 * t) * 128);
  float a0 = 0.f, a1 = 0.f, a2 = 0.f, a3 = 0.f;
#pragma unroll
  for (int c = 0; c < 16; c++) {
    const float* ap = &ash[c * 8];
    a0 += dot8(lv[c], ap);
    a1 += dot8(lv[16 + c], ap);
    a2 += dot8(lv[32 + c], ap);
    a3 += dot8(lv[48 + c], ap);
  }
  float l[4];
  l[0] = a0 * INV_NORM;
  l[1] = a1 * INV_NORM;
  l[2] = (4 * t + 2 < 510) ? a2 * INV_NORM : bl;  // k=510 -> blank
  l[3] = (4 * t + 3 < 510) ? a3 * INV_NORM : bl;  // k=511 -> blank
  float lmax = fmaxf(fmaxf(l[0], l[1]), fmaxf(l[2], l[3]));
  float m = wmax(lmax);
  __syncthreads();  // red reuse
  if (lane == 0) red[wid] = m;
  __syncthreads();
  float M = fmaxf(red[0], red[1]);
  float se = 0.f;
#pragma unroll
  for (int i = 0; i < 4; i++) se += expf(l[i] - M);
  float ssum = wsum(se);
  __syncthreads();  // red reuse
  if (lane == 0) red[wid] = ssum;
  __syncthreads();
  float S = red[0] + red[1];
  float logZ = M + logf(S);
  size_t nb = (size_t)n * 512 + 4 * t;
  size_t lpb = (size_t)OUT_LP + ((size_t)p * 32 + b) * 512 + 4 * t;
  float4 wv4, lg4, lp4;
  u16 ab4[4];
  float* lpv = &lp4.x;
  float* wvv = &wv4.x;
  float* lgv = &lg4.x;
#pragma unroll
  for (int i = 0; i < 4; i++) {
    float lp = l[i] - logZ;
    float w = expf(lp);
    lpv[i] = lp;
    wvv[i] = w;
    lgv[i] = l[i];
    ab4[i] = f2b(w);
  }
  *(float4*)(out + OUT_W + nb) = wv4;
  *(float4*)(out + OUT_LOG + nb) = lg4;
  *(float4*)(out + lpb) = lp4;
  *(uint2*)(Abf + nb) = *(uint2*)ab4;
}

// ---------------- K4: S_out = (weights @ sprite) permuted, bf16 MFMA -------
// BK=64, 8 k-iters, XOR k-chunk swizzle (global side) for conflict-free LDS.
__global__ __launch_bounds__(256) void k_gemm(const u16* __restrict__ A,
                                              const u16* __restrict__ Bt,
                                              float* __restrict__ out) {
  __shared__ u16 As[128 * 64];
  __shared__ u16 Bs[128 * 64];
  int tid = threadIdx.x;
  int wid = tid >> 6, lane = tid & 63;
  int nBase = blockIdx.x * 128;
  int mBase = blockIdx.y * 128;
  int wm = wid >> 1, wn = wid & 1;
  int quad = lane >> 4, r16 = lane & 15;
  f32x4 acc[4][4];
#pragma unroll
  for (int i = 0; i < 4; i++)
#pragma unroll
    for (int j = 0; j < 4; j++) acc[i][j] = (f32x4){0.f, 0.f, 0.f, 0.f};

  int srow8 = wid * 8 + (lane >> 3);           // row within a 32-row pass
  int kx = ((lane & 7) ^ (lane >> 3)) * 8;     // swizzled k-chunk (elements)
  char* ldsA = (char*)As + wid * 1024;
  char* ldsB = (char*)Bs + wid * 1024;
  int sw = r16 & 7;                            // read-side XOR key

  for (int kt = 0; kt < 8; kt++) {
    int k0 = kt * 64;
#pragma unroll
    for (int q = 0; q < 4; q++) {
      int row = q * 32 + srow8;
      const u16* ga = A + (size_t)(mBase + row) * 512 + k0 + kx;
      const u16* gb = Bt + (size_t)(nBase + row) * 512 + k0 + kx;
      __builtin_amdgcn_global_load_lds(
          (__attribute__((address_space(1))) void*)ga,
          (__attribute__((address_space(3))) void*)(ldsA + q * 4096), 16, 0, 0);
      __builtin_amdgcn_global_load_lds(
          (__attribute__((address_space(1))) void*)gb,
          (__attribute__((address_space(3))) void*)(ldsB + q * 4096), 16, 0, 0);
    }
    __syncthreads();
#pragma unroll
    for (int kk = 0; kk < 2; kk++) {
      int ch = ((quad + 4 * kk) ^ sw) * 8;     // LDS chunk holding global chunk
      bf16x8 af[4], bfr[4];
#pragma unroll
      for (int i = 0; i < 4; i++)
        af[i] = *(const bf16x8*)&As[(wm * 64 + i * 16 + r16) * 64 + ch];
#pragma unroll
      for (int j = 0; j < 4; j++)
        bfr[j] = *(const bf16x8*)&Bs[(wn * 64 + j * 16 + r16) * 64 + ch];
#pragma unroll
      for (int i = 0; i < 4; i++)
#pragma unroll
        for (int j = 0; j < 4; j++)
          acc[i][j] = __builtin_amdgcn_mfma_f32_16x16x32_bf16(af[i], bfr[j],
                                                              acc[i][j], 0, 0, 0);
    }
    __syncthreads();
  }
#pragma unroll
  for (int i = 0; i < 4; i++) {
#pragma unroll
    for (int r = 0; r < 4; r++) {
      int mg = mBase + wm * 64 + i * 16 + quad * 4 + r;
      size_t orow = (size_t)((mg & 127) * 32 + (mg >> 7));  // p*32 + b
      float* orp = out + OUT_S + orow * 16384 + nBase + wn * 64 + r16;
#pragma unroll
      for (int j = 0; j < 4; j++) orp[j * 16] = acc[i][j][r];
    }
  }
}

extern "C" void kernel_launch(void* const* d_in, const int* in_sizes, int n_in,
                              void* d_out, int out_size, void* d_ws, size_t ws_size,
                              hipStream_t stream) {
  const float* x = (const float*)d_in[0];
  const float* latents = (const float*)d_in[1];
  const float* blank = (const float*)d_in[2];
  const float* lw = (const float*)d_in[3];
  const float* lb = (const float*)d_in[4];
  const float* aw = (const float*)d_in[5];
  const float* ab = (const float*)d_in[6];
  const float* proto = (const float*)d_in[7];
  const float* masks = (const float*)d_in[8];
  float* out = (float*)d_out;
  u16* ws16 = (u16*)d_ws;
  u16* Bt = ws16 + WS_BT;
  u16* latbf = ws16 + WS_LAT;
  u16* Abf = ws16 + WS_A;

  k_lat<<<510, 128, 0, stream>>>(latents, lw, lb, latbf);
  k_tr<<<dim3(256, 8), 256, 0, stream>>>(proto, masks, Bt);
  k_rows<<<4096, 128, 0, stream>>>(x, aw, ab, blank, latbf, out, Abf);
  k_gemm<<<dim3(128, 32), 256, 0, stream>>>(Abf, Bt, out);
}